// Round 2
// baseline (241.985 us; speedup 1.0000x reference)
//
#include <hip/hip_runtime.h>

#define BETA_F   1e-7f
#define LAMBDA_F 1e-8f

// problem sizes
#define NB   4
#define CO   21
#define HWSZ 262144      // 512*512
#define NBC  84          // NB*CO
#define NPIX 1024        // 32*32

// ws layout in floats
#define OFF_FO    0                         // 84*1024 = 86016
#define OFF_GSUM  86016                     // 4*1024*32 = 131072
#define OFF_INVN  (86016 + 131072)          // 217088, 4096 floats
#define OFF_RMAX  (217088 + 4096)           // 221184, 4096 floats
#define OFF_LS    (221184 + 4096)           // 225280, 84*7 = 588
#define OFF_ACC   (225280 + 588)            // 225868, 4
#define ZERO_START OFF_RMAX
#define ZERO_COUNT (4096 + 588 + 4)         // 4688

// ---------------- zero the atomic-accumulated regions ----------------
__global__ void k_zero(float* __restrict__ ws) {
    int i = blockIdx.x * 256 + threadIdx.x;
    if (i < ZERO_COUNT) ws[ZERO_START + i] = 0.f;
}

// ---------------- levelset partial sums ----------------
// grid (32 slices, 84 bc), 256 thr. ws_ls[bc*7 + {num0,num1,num2,s20,s21,s22,den}]
__global__ __launch_bounds__(256) void k_ls(const float* __restrict__ outp,
                                            const float* __restrict__ tgt,
                                            float* __restrict__ ws) {
    const int slice = blockIdx.x, bc = blockIdx.y;
    const int b = bc / 21;
    const int tid = threadIdx.x;
    const float4* o4 = (const float4*)(outp + (size_t)bc * HWSZ + slice * 8192);
    const float4* t4 = (const float4*)(tgt + (size_t)b * (3 * HWSZ) + slice * 8192);
    float n0 = 0, n1 = 0, n2 = 0, q0 = 0, q1 = 0, q2 = 0, dn = 0;
    for (int i = tid; i < 2048; i += 256) {
        float4 o  = o4[i];
        float4 ta = t4[i];
        float4 tb = t4[i + 65536];    // +262144 floats
        float4 tc = t4[i + 131072];
        dn += o.x + o.y + o.z + o.w;
        n0 += ta.x*o.x + ta.y*o.y + ta.z*o.z + ta.w*o.w;
        q0 += ta.x*ta.x*o.x + ta.y*ta.y*o.y + ta.z*ta.z*o.z + ta.w*ta.w*o.w;
        n1 += tb.x*o.x + tb.y*o.y + tb.z*o.z + tb.w*o.w;
        q1 += tb.x*tb.x*o.x + tb.y*tb.y*o.y + tb.z*tb.z*o.z + tb.w*tb.w*o.w;
        n2 += tc.x*o.x + tc.y*o.y + tc.z*o.z + tc.w*o.w;
        q2 += tc.x*tc.x*o.x + tc.y*tc.y*o.y + tc.z*tc.z*o.z + tc.w*tc.w*o.w;
    }
    float vals[7] = {n0, n1, n2, q0, q1, q2, dn};
    __shared__ float red[4][7];
    #pragma unroll
    for (int j = 0; j < 7; ++j) {
        float v = vals[j];
        #pragma unroll
        for (int off = 32; off; off >>= 1) v += __shfl_xor(v, off);
        if ((tid & 63) == 0) red[tid >> 6][j] = v;
    }
    __syncthreads();
    if (tid < 7) {
        float s = red[0][tid] + red[1][tid] + red[2][tid] + red[3][tid];
        atomicAdd(&ws[OFF_LS + bc * 7 + tid], s);
    }
}

// ---------------- bilinear resize 64x64 -> 32x32 (align_corners) ----------------
__global__ void k_resize(const float* __restrict__ fo_in, float* __restrict__ ws) {
    const int bc = blockIdx.x;
    const int tid = threadIdx.x;          // 1024
    const int oy = tid >> 5, ox = tid & 31;
    const float R = 63.0f / 31.0f;        // same f32 arithmetic as JAX ref
    float sy = oy * R, sx = ox * R;
    int y0 = (int)sy, x0 = (int)sx;
    int y1 = min(y0 + 1, 63), x1 = min(x0 + 1, 63);
    float wy = sy - (float)y0, wx = sx - (float)x0;
    const float* im = fo_in + bc * 4096;
    float v00 = im[y0 * 64 + x0], v01 = im[y0 * 64 + x1];
    float v10 = im[y1 * 64 + x0], v11 = im[y1 * 64 + x1];
    float top = v00 * (1.f - wx) + v01 * wx;
    float bot = v10 * (1.f - wx) + v11 * wx;
    ws[OFF_FO + bc * NPIX + tid] = top * (1.f - wy) + bot * wy;
}

// ---------------- inverse norms of f_sem pixels ----------------
// grid 64 (b*16 + pixgroup), 256 thr
__global__ void k_norm(const float* __restrict__ fsem, float* __restrict__ ws) {
    const int b = blockIdx.x >> 4, pg = blockIdx.x & 15;
    const int p0 = pg * 64;
    const int pi = threadIdx.x & 63, cg = threadIdx.x >> 6;
    float s = 0.f;
    for (int c = cg; c < 256; c += 4) {
        float v = fsem[(b * 256 + c) * 1024 + p0 + pi];
        s += v * v;
    }
    __shared__ float red[4][64];
    red[cg][pi] = s;
    __syncthreads();
    if (threadIdx.x < 64) {
        float t = red[0][threadIdx.x] + red[1][threadIdx.x] +
                  red[2][threadIdx.x] + red[3][threadIdx.x];
        ws[OFF_INVN + b * 1024 + p0 + threadIdx.x] = 1.f / fmaxf(sqrtf(t), 1e-12f);
    }
}

// ---------------- gram: tau rows -> group sums + row max ----------------
// grid (ct=8, rt=8, b=4), 256 thr. 128x128 tile, 8x8 regs/thread.
// LDS layout: k-major float4 tiles, bit-rotate+XOR swizzle for bank spread.
__device__ __forceinline__ int swz(int p4, int k) {
    int s = (p4 >> 1) | ((p4 & 1) << 4);   // rotate: parity bit to bit4
    return s ^ (k & 7);
}

__global__ __launch_bounds__(256) void k_gram(const float* __restrict__ fsem,
                                              float* __restrict__ ws) {
    const int ct = blockIdx.x, rt = blockIdx.y, b = blockIdx.z;
    const int r0 = rt * 128, c0 = ct * 128;
    const int tid = threadIdx.x;
    __shared__ float4 As4[64 * 32];
    __shared__ float4 Bs4[64 * 32];
    __shared__ float  gsum_s[512];   // [row][4 groups]
    __shared__ int    rmax_s[128];
    for (int i = tid; i < 512; i += 256) gsum_s[i] = 0.f;
    if (tid < 128) rmax_s[tid] = 0;

    const int tr = tid >> 4, tc = tid & 15;
    float acc[8][8];
    #pragma unroll
    for (int i = 0; i < 8; ++i)
        #pragma unroll
        for (int j = 0; j < 8; ++j) acc[i][j] = 0.f;

    const int kl = tid >> 5, p4s = tid & 31;
    for (int kk = 0; kk < 4; ++kk) {
        __syncthreads();
        #pragma unroll
        for (int q = 0; q < 8; ++q) {
            int k = kl + q * 8;
            const float* srcA = &fsem[(b * 256 + kk * 64 + k) * 1024 + r0 + p4s * 4];
            const float* srcB = &fsem[(b * 256 + kk * 64 + k) * 1024 + c0 + p4s * 4];
            float4 va = *(const float4*)srcA;
            float4 vb = *(const float4*)srcB;
            int sl = swz(p4s, k);
            As4[k * 32 + sl] = va;
            Bs4[k * 32 + sl] = vb;
        }
        __syncthreads();
        #pragma unroll 4
        for (int k = 0; k < 64; ++k) {
            int k7 = k & 7;
            float4 a0 = As4[k * 32 + (tr ^ k7)];
            float4 a1 = As4[k * 32 + ((tr ^ k7) | 16)];
            float4 b0 = Bs4[k * 32 + (tc ^ k7)];
            float4 b1 = Bs4[k * 32 + ((tc ^ k7) | 16)];
            float a[8]  = {a0.x, a0.y, a0.z, a0.w, a1.x, a1.y, a1.z, a1.w};
            float bb[8] = {b0.x, b0.y, b0.z, b0.w, b1.x, b1.y, b1.z, b1.w};
            #pragma unroll
            for (int i = 0; i < 8; ++i)
                #pragma unroll
                for (int j = 0; j < 8; ++j)
                    acc[i][j] += a[i] * bb[j];
        }
    }

    // epilogue: tau = relu(dot)*invn_r*invn_c; accumulate group sums + row max
    float ir[8], ic[8];
    #pragma unroll
    for (int i = 0; i < 8; ++i) {
        ir[i] = ws[OFF_INVN + b * 1024 + r0 + tr * 8 + i];
        ic[i] = ws[OFF_INVN + b * 1024 + c0 + tc * 8 + i];
    }
    const int g = tc >> 2;   // 8 cols of a thread never cross a 32-col group
    #pragma unroll
    for (int i = 0; i < 8; ++i) {
        float s = 0.f, m = 0.f;
        #pragma unroll
        for (int j = 0; j < 8; ++j) {
            float v = fmaxf(acc[i][j], 0.f) * ir[i] * ic[j];
            s += v;
            m = fmaxf(m, v);
        }
        int row = tr * 8 + i;
        atomicAdd(&gsum_s[row * 4 + g], s);
        atomicMax(&rmax_s[row], __float_as_int(m));
    }
    __syncthreads();
    for (int i = tid; i < 512; i += 256) {
        int row = i >> 2, gg = i & 3;
        ws[OFF_GSUM + (b * 1024 + r0 + row) * 32 + ct * 4 + gg] = gsum_s[i];
    }
    if (tid < 128)
        atomicMax((int*)&ws[OFF_RMAX + b * 1024 + r0 + tid], rmax_s[tid]);
}

// ---------------- final TV contraction: sum A[b,c,r,k]*t[b,r,k] ----------------
// grid (rchunk=4, bc=84), 256 thr
__global__ __launch_bounds__(256) void k_tv(const float* __restrict__ ws,
                                            float* __restrict__ acc_out) {
    const int bc = blockIdx.y;
    const int b = bc / 21;
    const int tid = threadIdx.x;
    __shared__ float4 fo4[256];
    const float4* src = (const float4*)(ws + OFF_FO + bc * NPIX);
    fo4[tid] = src[tid];
    __syncthreads();
    const int r = blockIdx.x * 256 + tid;
    const float v = ((const float*)fo4)[r];
    float ak[32];
    #pragma unroll
    for (int k = 0; k < 32; ++k) ak[k] = 0.f;
    #pragma unroll 4
    for (int h = 0; h < 32; ++h) {
        #pragma unroll
        for (int k4 = 0; k4 < 8; ++k4) {
            float4 f = fo4[h * 8 + k4];
            ak[k4 * 4 + 0] += fabsf(v - f.x);
            ak[k4 * 4 + 1] += fabsf(v - f.y);
            ak[k4 * 4 + 2] += fabsf(v - f.z);
            ak[k4 * 4 + 3] += fabsf(v - f.w);
        }
    }
    const float rm = ws[OFF_RMAX + b * 1024 + r];
    const float inv = 1.f / (rm + 1e-5f);
    const float* t = ws + OFF_GSUM + (b * 1024 + r) * 32;
    float dot = 0.f;
    #pragma unroll
    for (int k = 0; k < 32; ++k) dot += ak[k] * t[k];
    float part = dot * inv;
    #pragma unroll
    for (int off = 32; off; off >>= 1) part += __shfl_xor(part, off);
    __shared__ float red[4];
    if ((tid & 63) == 0) red[tid >> 6] = part;
    __syncthreads();
    if (tid == 0) atomicAdd(acc_out, red[0] + red[1] + red[2] + red[3]);
}

// ---------------- combine to 3 outputs ----------------
__global__ void k_combine(const float* __restrict__ ws, float* __restrict__ out) {
    const int tid = threadIdx.x;   // 128
    float v = 0.f;
    if (tid < NBC) {
        const float* p = ws + OFF_LS + tid * 7;
        float den = p[6];
        v = (p[3] + p[4] + p[5]) - (p[0]*p[0] + p[1]*p[1] + p[2]*p[2]) / den;
    }
    #pragma unroll
    for (int off = 32; off; off >>= 1) v += __shfl_xor(v, off);
    __shared__ float red[2];
    if ((tid & 63) == 0) red[tid >> 6] = v;
    __syncthreads();
    if (tid == 0) {
        float lsv = (red[0] + red[1]) * 0.25f;     // / B
        float tvv = ws[OFF_ACC] * 0.25f;           // / B
        out[0] = lsv * BETA_F;
        out[1] = tvv * LAMBDA_F * BETA_F;
        out[2] = (lsv + tvv * LAMBDA_F) * BETA_F;
    }
}

extern "C" void kernel_launch(void* const* d_in, const int* in_sizes, int n_in,
                              void* d_out, int out_size, void* d_ws, size_t ws_size,
                              hipStream_t stream) {
    const float* output   = (const float*)d_in[0];   // (4,21,512,512)
    const float* target   = (const float*)d_in[1];   // (4,3,512,512)
    const float* f_sem    = (const float*)d_in[2];   // (4,256,32,32)
    const float* f_output = (const float*)d_in[3];   // (4,21,64,64)
    // d_in[4] = use_NonLocal_TV, fixed to 1 by setup_inputs
    float* ws  = (float*)d_ws;
    float* out = (float*)d_out;

    hipLaunchKernelGGL(k_zero,    dim3((ZERO_COUNT + 255) / 256), dim3(256), 0, stream, ws);
    hipLaunchKernelGGL(k_ls,      dim3(32, 84), dim3(256),  0, stream, output, target, ws);
    hipLaunchKernelGGL(k_resize,  dim3(84),     dim3(1024), 0, stream, f_output, ws);
    hipLaunchKernelGGL(k_norm,    dim3(64),     dim3(256),  0, stream, f_sem, ws);
    hipLaunchKernelGGL(k_gram,    dim3(8, 8, 4), dim3(256), 0, stream, f_sem, ws);
    hipLaunchKernelGGL(k_tv,      dim3(4, 84),  dim3(256),  0, stream, ws, ws + OFF_ACC);
    hipLaunchKernelGGL(k_combine, dim3(1),      dim3(128),  0, stream, ws, out);
}

// Round 3
// 224.504 us; speedup vs baseline: 1.0779x; 1.0779x over previous
//
#include <hip/hip_runtime.h>

#define BETA_F   1e-7f
#define LAMBDA_F 1e-8f

// problem sizes
#define HWSZ 262144      // 512*512
#define NBC  84          // NB*CO
#define NPIX 1024        // 32*32

// ws layout in floats
#define OFF_FO    0                         // 84*1024 = 86016
#define OFF_GSUM  86016                     // 4*1024*32 = 131072
#define OFF_INVN  (86016 + 131072)          // 217088, 4096 floats
#define OFF_RMAX  (217088 + 4096)           // 221184, 4096 floats
#define OFF_LS    (221184 + 4096)           // 225280, 84*7 = 588
#define OFF_ACC   (225280 + 588)            // 225868, 4
#define ZERO_START OFF_RMAX
#define ZERO_COUNT (4096 + 588 + 4)         // 4688

// ================= prep: zero | resize | norm (block-range specialized) ======
// blocks [0,19): zero atomics region; [19,103): bilinear resize 84 maps;
// [103,167): f_sem pixel inverse-norms.
__global__ __launch_bounds__(256) void k_prep(const float* __restrict__ fo_in,
                                              const float* __restrict__ fsem,
                                              float* __restrict__ ws) {
    const int bid = blockIdx.x, tid = threadIdx.x;
    if (bid < 19) {
        int i = bid * 256 + tid;
        if (i < ZERO_COUNT) ws[ZERO_START + i] = 0.f;
    } else if (bid < 103) {
        const int bc = bid - 19;
        const float* im = fo_in + bc * 4096;
        for (int p = tid; p < 1024; p += 256) {
            const int oy = p >> 5, ox = p & 31;
            const float R = 63.0f / 31.0f;      // same f32 arithmetic as JAX ref
            float sy = oy * R, sx = ox * R;
            int y0 = (int)sy, x0 = (int)sx;
            int y1 = min(y0 + 1, 63), x1 = min(x0 + 1, 63);
            float wy = sy - (float)y0, wx = sx - (float)x0;
            float v00 = im[y0 * 64 + x0], v01 = im[y0 * 64 + x1];
            float v10 = im[y1 * 64 + x0], v11 = im[y1 * 64 + x1];
            float top = v00 * (1.f - wx) + v01 * wx;
            float bot = v10 * (1.f - wx) + v11 * wx;
            ws[OFF_FO + bc * NPIX + p] = top * (1.f - wy) + bot * wy;
        }
    } else {
        const int blk = bid - 103;
        const int b = blk >> 4, pg = blk & 15;
        const int p0 = pg * 64;
        const int pi = tid & 63, cg = tid >> 6;
        float s = 0.f;
        for (int c = cg; c < 256; c += 4) {
            float v = fsem[(b * 256 + c) * 1024 + p0 + pi];
            s += v * v;
        }
        __shared__ float red[4][64];
        red[cg][pi] = s;
        __syncthreads();
        if (tid < 64) {
            float t = red[0][tid] + red[1][tid] + red[2][tid] + red[3][tid];
            ws[OFF_INVN + b * 1024 + p0 + tid] = 1.f / fmaxf(sqrtf(t), 1e-12f);
        }
    }
}

// ================= main: gram (compute-bound) || levelset (HBM-bound) ========
// blocks [0,256): gram 128x128 tiles; blocks [256,2944): levelset partials.
// One kernel so the two regimes co-schedule on the CUs (m114 overlap).
__device__ __forceinline__ int swz(int p4, int k) {
    int s = (p4 >> 1) | ((p4 & 1) << 4);   // rotate: parity bit to bit4
    return s ^ (k & 7);
}

__global__ __launch_bounds__(256) void k_main(const float* __restrict__ outp,
                                              const float* __restrict__ tgt,
                                              const float* __restrict__ fsem,
                                              float* __restrict__ ws) {
    __shared__ __align__(16) char smem[68096];
    const int tid = threadIdx.x;

    if (blockIdx.x < 256) {
        // ---------------- gram: tau rows -> group sums + row max -------------
        float4* As4    = (float4*)smem;             // 32768 B
        float4* Bs4    = (float4*)(smem + 32768);   // 32768 B
        float*  gsum_s = (float*)(smem + 65536);    // 2048 B  [row][4 groups]
        int*    rmax_s = (int*)(smem + 67584);      // 512 B
        const int bid = blockIdx.x;
        const int ct = bid & 7, rt = (bid >> 3) & 7, b = bid >> 6;
        const int r0 = rt * 128, c0 = ct * 128;
        for (int i = tid; i < 512; i += 256) gsum_s[i] = 0.f;
        if (tid < 128) rmax_s[tid] = 0;

        const int tr = tid >> 4, tc = tid & 15;
        float acc[8][8];
        #pragma unroll
        for (int i = 0; i < 8; ++i)
            #pragma unroll
            for (int j = 0; j < 8; ++j) acc[i][j] = 0.f;

        const int kl = tid >> 5, p4s = tid & 31;
        for (int kk = 0; kk < 4; ++kk) {
            __syncthreads();
            #pragma unroll
            for (int q = 0; q < 8; ++q) {
                int k = kl + q * 8;
                const float* srcA = &fsem[(b * 256 + kk * 64 + k) * 1024 + r0 + p4s * 4];
                const float* srcB = &fsem[(b * 256 + kk * 64 + k) * 1024 + c0 + p4s * 4];
                float4 va = *(const float4*)srcA;
                float4 vb = *(const float4*)srcB;
                int sl = swz(p4s, k);
                As4[k * 32 + sl] = va;
                Bs4[k * 32 + sl] = vb;
            }
            __syncthreads();
            #pragma unroll 4
            for (int k = 0; k < 64; ++k) {
                int k7 = k & 7;
                float4 a0 = As4[k * 32 + (tr ^ k7)];
                float4 a1 = As4[k * 32 + ((tr ^ k7) | 16)];
                float4 b0 = Bs4[k * 32 + (tc ^ k7)];
                float4 b1 = Bs4[k * 32 + ((tc ^ k7) | 16)];
                float a[8]  = {a0.x, a0.y, a0.z, a0.w, a1.x, a1.y, a1.z, a1.w};
                float bb[8] = {b0.x, b0.y, b0.z, b0.w, b1.x, b1.y, b1.z, b1.w};
                #pragma unroll
                for (int i = 0; i < 8; ++i)
                    #pragma unroll
                    for (int j = 0; j < 8; ++j)
                        acc[i][j] += a[i] * bb[j];
            }
        }

        float ir[8], ic[8];
        #pragma unroll
        for (int i = 0; i < 8; ++i) {
            ir[i] = ws[OFF_INVN + b * 1024 + r0 + tr * 8 + i];
            ic[i] = ws[OFF_INVN + b * 1024 + c0 + tc * 8 + i];
        }
        const int g = tc >> 2;   // a thread's 8 cols never cross a 32-col group
        #pragma unroll
        for (int i = 0; i < 8; ++i) {
            float s = 0.f, m = 0.f;
            #pragma unroll
            for (int j = 0; j < 8; ++j) {
                float v = fmaxf(acc[i][j], 0.f) * ir[i] * ic[j];
                s += v;
                m = fmaxf(m, v);
            }
            int row = tr * 8 + i;
            atomicAdd(&gsum_s[row * 4 + g], s);
            atomicMax(&rmax_s[row], __float_as_int(m));
        }
        __syncthreads();
        for (int i = tid; i < 512; i += 256) {
            int row = i >> 2, gg = i & 3;
            ws[OFF_GSUM + (b * 1024 + r0 + row) * 32 + ct * 4 + gg] = gsum_s[i];
        }
        if (tid < 128)
            atomicMax((int*)&ws[OFF_RMAX + b * 1024 + r0 + tid], rmax_s[tid]);
    } else {
        // ---------------- levelset partial sums ------------------------------
        float (*red)[7] = (float (*)[7])smem;
        const int blk = blockIdx.x - 256;
        const int slice = blk & 31, bc = blk >> 5;
        const int b = bc / 21;
        const float4* o4 = (const float4*)(outp + (size_t)bc * HWSZ + slice * 8192);
        const float4* t4 = (const float4*)(tgt + (size_t)b * (3 * HWSZ) + slice * 8192);
        float n0 = 0, n1 = 0, n2 = 0, q0 = 0, q1 = 0, q2 = 0, dn = 0;
        #pragma unroll 2
        for (int i = tid; i < 2048; i += 256) {
            float4 o  = o4[i];
            float4 ta = t4[i];
            float4 tb = t4[i + 65536];    // +262144 floats
            float4 tc = t4[i + 131072];
            dn += o.x + o.y + o.z + o.w;
            n0 += ta.x*o.x + ta.y*o.y + ta.z*o.z + ta.w*o.w;
            q0 += ta.x*ta.x*o.x + ta.y*ta.y*o.y + ta.z*ta.z*o.z + ta.w*ta.w*o.w;
            n1 += tb.x*o.x + tb.y*o.y + tb.z*o.z + tb.w*o.w;
            q1 += tb.x*tb.x*o.x + tb.y*tb.y*o.y + tb.z*tb.z*o.z + tb.w*tb.w*o.w;
            n2 += tc.x*o.x + tc.y*o.y + tc.z*o.z + tc.w*o.w;
            q2 += tc.x*tc.x*o.x + tc.y*tc.y*o.y + tc.z*tc.z*o.z + tc.w*tc.w*o.w;
        }
        float vals[7] = {n0, n1, n2, q0, q1, q2, dn};
        #pragma unroll
        for (int j = 0; j < 7; ++j) {
            float v = vals[j];
            #pragma unroll
            for (int off = 32; off; off >>= 1) v += __shfl_xor(v, off);
            if ((tid & 63) == 0) red[tid >> 6][j] = v;
        }
        __syncthreads();
        if (tid < 7) {
            float s = red[0][tid] + red[1][tid] + red[2][tid] + red[3][tid];
            atomicAdd(&ws[OFF_LS + bc * 7 + tid], s);
        }
    }
}

// ================= final TV contraction: sum A[b,c,r,k]*t[b,r,k] =============
__global__ __launch_bounds__(256) void k_tv(const float* __restrict__ ws,
                                            float* __restrict__ acc_out) {
    const int bc = blockIdx.y;
    const int b = bc / 21;
    const int tid = threadIdx.x;
    __shared__ float4 fo4[256];
    const float4* src = (const float4*)(ws + OFF_FO + bc * NPIX);
    fo4[tid] = src[tid];
    __syncthreads();
    const int r = blockIdx.x * 256 + tid;
    const float v = ((const float*)fo4)[r];
    float ak[32];
    #pragma unroll
    for (int k = 0; k < 32; ++k) ak[k] = 0.f;
    #pragma unroll 4
    for (int h = 0; h < 32; ++h) {
        #pragma unroll
        for (int k4 = 0; k4 < 8; ++k4) {
            float4 f = fo4[h * 8 + k4];
            ak[k4 * 4 + 0] += fabsf(v - f.x);
            ak[k4 * 4 + 1] += fabsf(v - f.y);
            ak[k4 * 4 + 2] += fabsf(v - f.z);
            ak[k4 * 4 + 3] += fabsf(v - f.w);
        }
    }
    const float rm = ws[OFF_RMAX + b * 1024 + r];
    const float inv = 1.f / (rm + 1e-5f);
    const float* t = ws + OFF_GSUM + (b * 1024 + r) * 32;
    float dot = 0.f;
    #pragma unroll
    for (int k = 0; k < 32; ++k) dot += ak[k] * t[k];
    float part = dot * inv;
    #pragma unroll
    for (int off = 32; off; off >>= 1) part += __shfl_xor(part, off);
    __shared__ float red[4];
    if ((tid & 63) == 0) red[tid >> 6] = part;
    __syncthreads();
    if (tid == 0) atomicAdd(acc_out, red[0] + red[1] + red[2] + red[3]);
}

// ================= combine to 3 outputs ======================================
__global__ void k_combine(const float* __restrict__ ws, float* __restrict__ out) {
    const int tid = threadIdx.x;   // 128
    float v = 0.f;
    if (tid < NBC) {
        const float* p = ws + OFF_LS + tid * 7;
        float den = p[6];
        v = (p[3] + p[4] + p[5]) - (p[0]*p[0] + p[1]*p[1] + p[2]*p[2]) / den;
    }
    #pragma unroll
    for (int off = 32; off; off >>= 1) v += __shfl_xor(v, off);
    __shared__ float red[2];
    if ((tid & 63) == 0) red[tid >> 6] = v;
    __syncthreads();
    if (tid == 0) {
        float lsv = (red[0] + red[1]) * 0.25f;     // / B
        float tvv = ws[OFF_ACC] * 0.25f;           // / B
        out[0] = lsv * BETA_F;
        out[1] = tvv * LAMBDA_F * BETA_F;
        out[2] = (lsv + tvv * LAMBDA_F) * BETA_F;
    }
}

extern "C" void kernel_launch(void* const* d_in, const int* in_sizes, int n_in,
                              void* d_out, int out_size, void* d_ws, size_t ws_size,
                              hipStream_t stream) {
    const float* output   = (const float*)d_in[0];   // (4,21,512,512)
    const float* target   = (const float*)d_in[1];   // (4,3,512,512)
    const float* f_sem    = (const float*)d_in[2];   // (4,256,32,32)
    const float* f_output = (const float*)d_in[3];   // (4,21,64,64)
    // d_in[4] = use_NonLocal_TV, fixed to 1 by setup_inputs
    float* ws  = (float*)d_ws;
    float* out = (float*)d_out;

    hipLaunchKernelGGL(k_prep,    dim3(167),    dim3(256), 0, stream, f_output, f_sem, ws);
    hipLaunchKernelGGL(k_main,    dim3(2944),   dim3(256), 0, stream, output, target, f_sem, ws);
    hipLaunchKernelGGL(k_tv,      dim3(4, 84),  dim3(256), 0, stream, ws, ws + OFF_ACC);
    hipLaunchKernelGGL(k_combine, dim3(1),      dim3(128), 0, stream, ws, out);
}

// Round 6
// 216.384 us; speedup vs baseline: 1.1183x; 1.0375x over previous
//
#include <hip/hip_runtime.h>

#define BETA_F   1e-7f
#define LAMBDA_F 1e-8f

// problem sizes
#define HWSZ 262144      // 512*512
#define NBC  84          // NB*CO
#define NPIX 1024        // 32*32

// ws layout in floats
#define OFF_FO    0                         // 84*1024 = 86016
#define OFF_GSUM  86016                     // 4*1024*32 = 131072
#define OFF_INVN  (86016 + 131072)          // 217088, 4096 floats
#define OFF_RMAX  (217088 + 4096)           // 221184, 4096 floats
#define OFF_LS    (221184 + 4096)           // 225280, 84*7 = 588
#define OFF_ACC   (225280 + 588)            // 225868, 4
#define ZERO_START OFF_RMAX
#define ZERO_COUNT (4096 + 588 + 4)         // 4688

#define N_GRAM_BLK 144                      // 4 batches * 36 upper-tri tiles

// upper-triangle tile lookup (rt <= ct)
__device__ const unsigned char RT_[36] =
    {0,0,0,0,0,0,0,0, 1,1,1,1,1,1,1, 2,2,2,2,2,2, 3,3,3,3,3, 4,4,4,4, 5,5,5, 6,6, 7};
__device__ const unsigned char CT_[36] =
    {0,1,2,3,4,5,6,7, 1,2,3,4,5,6,7, 2,3,4,5,6,7, 3,4,5,6,7, 4,5,6,7, 5,6,7, 6,7, 7};

// ================= prep: zero | resize | norm (block-range specialized) ======
__global__ __launch_bounds__(256) void k_prep(const float* __restrict__ fo_in,
                                              const float* __restrict__ fsem,
                                              float* __restrict__ ws) {
    const int bid = blockIdx.x, tid = threadIdx.x;
    if (bid < 19) {
        int i = bid * 256 + tid;
        if (i < ZERO_COUNT) ws[ZERO_START + i] = 0.f;
    } else if (bid < 103) {
        const int bc = bid - 19;
        const float* im = fo_in + bc * 4096;
        for (int p = tid; p < 1024; p += 256) {
            const int oy = p >> 5, ox = p & 31;
            const float R = 63.0f / 31.0f;      // same f32 arithmetic as JAX ref
            float sy = oy * R, sx = ox * R;
            int y0 = (int)sy, x0 = (int)sx;
            int y1 = min(y0 + 1, 63), x1 = min(x0 + 1, 63);
            float wy = sy - (float)y0, wx = sx - (float)x0;
            float v00 = im[y0 * 64 + x0], v01 = im[y0 * 64 + x1];
            float v10 = im[y1 * 64 + x0], v11 = im[y1 * 64 + x1];
            float top = v00 * (1.f - wx) + v01 * wx;
            float bot = v10 * (1.f - wx) + v11 * wx;
            ws[OFF_FO + bc * NPIX + p] = top * (1.f - wy) + bot * wy;
        }
    } else {
        const int blk = bid - 103;
        const int b = blk >> 4, pg = blk & 15;
        const int p0 = pg * 64;
        const int pi = tid & 63, cg = tid >> 6;
        float s = 0.f;
        for (int c = cg; c < 256; c += 4) {
            float v = fsem[(b * 256 + c) * 1024 + p0 + pi];
            s += v * v;
        }
        __shared__ float red[4][64];
        red[cg][pi] = s;
        __syncthreads();
        if (tid < 64) {
            float t = red[0][tid] + red[1][tid] + red[2][tid] + red[3][tid];
            ws[OFF_INVN + b * 1024 + p0 + tid] = 1.f / fmaxf(sqrtf(t), 1e-12f);
        }
    }
}

// ================= main: symmetric gram || levelset ==========================
// blocks [0,144): gram upper-tri 128x128 tiles (BK=16, 21.5 KB LDS);
// blocks [144,2832): levelset partials. Fused so HBM-streaming ls waves
// co-schedule with VALU-bound gram waves (m114); small LDS keeps occupancy up.
__device__ __forceinline__ int swz(int p4, int k) {
    int s = (p4 >> 1) | ((p4 & 1) << 4);   // rotate: parity bit to bit4
    return s ^ (k & 7);
}

__global__ __launch_bounds__(256) void k_main(const float* __restrict__ outp,
                                              const float* __restrict__ tgt,
                                              const float* __restrict__ fsem,
                                              float* __restrict__ ws) {
    __shared__ __align__(16) char smem[21504];
    const int tid = threadIdx.x;

    if (blockIdx.x < N_GRAM_BLK) {
        // ---------------- gram tile (rt<=ct): row-side + mirrored col-side ---
        float4* As4    = (float4*)smem;              // 8192 B  [16][32] f4
        float4* Bs4    = (float4*)(smem + 8192);     // 8192 B
        float*  gs_row = (float*)(smem + 16384);     // 2048 B  [128][4]
        float*  gs_col = (float*)(smem + 18432);     // 2048 B
        int*    rm_row = (int*)(smem + 20480);       // 512 B
        int*    rm_col = (int*)(smem + 20992);       // 512 B
        const int bid = blockIdx.x;
        const int b = bid / 36, t = bid % 36;
        const int rt = RT_[t], ct = CT_[t];
        const bool diag = (rt == ct);
        const int r0 = rt * 128, c0 = ct * 128;
        for (int i = tid; i < 512; i += 256) { gs_row[i] = 0.f; gs_col[i] = 0.f; }
        if (tid < 128) { rm_row[tid] = 0; rm_col[tid] = 0; }

        const int tr = tid >> 4, tc = tid & 15;
        float acc[8][8];
        #pragma unroll
        for (int i = 0; i < 8; ++i)
            #pragma unroll
            for (int j = 0; j < 8; ++j) acc[i][j] = 0.f;

        const int kl = tid >> 5, p4s = tid & 31;
        for (int kk = 0; kk < 16; ++kk) {
            __syncthreads();
            #pragma unroll
            for (int q = 0; q < 2; ++q) {
                int k = kl + q * 8;
                const float* srcA = &fsem[(b * 256 + kk * 16 + k) * 1024 + r0 + p4s * 4];
                const float* srcB = &fsem[(b * 256 + kk * 16 + k) * 1024 + c0 + p4s * 4];
                float4 va = *(const float4*)srcA;
                float4 vb = *(const float4*)srcB;
                int sl = swz(p4s, k);
                As4[k * 32 + sl] = va;
                Bs4[k * 32 + sl] = vb;
            }
            __syncthreads();
            #pragma unroll 4
            for (int k = 0; k < 16; ++k) {
                int k7 = k & 7;
                float4 a0 = As4[k * 32 + (tr ^ k7)];
                float4 a1 = As4[k * 32 + ((tr ^ k7) | 16)];
                float4 b0 = Bs4[k * 32 + (tc ^ k7)];
                float4 b1 = Bs4[k * 32 + ((tc ^ k7) | 16)];
                float a[8]  = {a0.x, a0.y, a0.z, a0.w, a1.x, a1.y, a1.z, a1.w};
                float bb[8] = {b0.x, b0.y, b0.z, b0.w, b1.x, b1.y, b1.z, b1.w};
                #pragma unroll
                for (int i = 0; i < 8; ++i)
                    #pragma unroll
                    for (int j = 0; j < 8; ++j)
                        acc[i][j] += a[i] * bb[j];
            }
        }

        float ir[8], ic[8];
        #pragma unroll
        for (int i = 0; i < 8; ++i) {
            ir[i] = ws[OFF_INVN + b * 1024 + r0 + tr * 8 + i];
            ic[i] = ws[OFF_INVN + b * 1024 + c0 + tc * 8 + i];
        }
        // row-side: rows r0+row, col-groups in ct-range
        const int gr = tc >> 2;   // thread's 8 cols stay in one 32-col group
        #pragma unroll
        for (int i = 0; i < 8; ++i) {
            float s = 0.f, m = 0.f;
            #pragma unroll
            for (int j = 0; j < 8; ++j) {
                float v = fmaxf(acc[i][j], 0.f) * ir[i] * ic[j];
                s += v;
                m = fmaxf(m, v);
            }
            int row = tr * 8 + i;
            atomicAdd(&gs_row[row * 4 + gr], s);
            atomicMax(&rm_row[row], __float_as_int(m));
        }
        // col-side (mirror, rt<ct only): rows c0+col, col-groups in rt-range
        if (!diag) {
            const int gc = tr >> 2;  // thread's 8 rows stay in one 32-row group
            #pragma unroll
            for (int j = 0; j < 8; ++j) {
                float s = 0.f, m = 0.f;
                #pragma unroll
                for (int i = 0; i < 8; ++i) {
                    float v = fmaxf(acc[i][j], 0.f) * ir[i] * ic[j];
                    s += v;
                    m = fmaxf(m, v);
                }
                int col = tc * 8 + j;
                atomicAdd(&gs_col[col * 4 + gc], s);
                atomicMax(&rm_col[col], __float_as_int(m));
            }
        }
        __syncthreads();
        for (int i = tid; i < 512; i += 256) {
            int row = i >> 2, gg = i & 3;
            ws[OFF_GSUM + (b * 1024 + r0 + row) * 32 + ct * 4 + gg] = gs_row[i];
            if (!diag)
                ws[OFF_GSUM + (b * 1024 + c0 + row) * 32 + rt * 4 + gg] = gs_col[i];
        }
        if (tid < 128) {
            atomicMax((int*)&ws[OFF_RMAX + b * 1024 + r0 + tid], rm_row[tid]);
            if (!diag)
                atomicMax((int*)&ws[OFF_RMAX + b * 1024 + c0 + tid], rm_col[tid]);
        }
    } else {
        // ---------------- levelset partial sums ------------------------------
        float (*red)[7] = (float (*)[7])smem;
        const int blk = blockIdx.x - N_GRAM_BLK;
        const int slice = blk & 31, bc = blk >> 5;
        const int b = bc / 21;
        const float4* o4 = (const float4*)(outp + (size_t)bc * HWSZ + slice * 8192);
        const float4* t4 = (const float4*)(tgt + (size_t)b * (3 * HWSZ) + slice * 8192);
        float n0 = 0, n1 = 0, n2 = 0, q0 = 0, q1 = 0, q2 = 0, dn = 0;
        #pragma unroll 2
        for (int i = tid; i < 2048; i += 256) {
            float4 o  = o4[i];
            float4 ta = t4[i];
            float4 tb = t4[i + 65536];    // +262144 floats
            float4 tc = t4[i + 131072];
            dn += o.x + o.y + o.z + o.w;
            n0 += ta.x*o.x + ta.y*o.y + ta.z*o.z + ta.w*o.w;
            q0 += ta.x*ta.x*o.x + ta.y*ta.y*o.y + ta.z*ta.z*o.z + ta.w*ta.w*o.w;
            n1 += tb.x*o.x + tb.y*o.y + tb.z*o.z + tb.w*o.w;
            q1 += tb.x*tb.x*o.x + tb.y*tb.y*o.y + tb.z*tb.z*o.z + tb.w*tb.w*o.w;
            n2 += tc.x*o.x + tc.y*o.y + tc.z*o.z + tc.w*o.w;
            q2 += tc.x*tc.x*o.x + tc.y*tc.y*o.y + tc.z*tc.z*o.z + tc.w*tc.w*o.w;
        }
        float vals[7] = {n0, n1, n2, q0, q1, q2, dn};
        #pragma unroll
        for (int j = 0; j < 7; ++j) {
            float v = vals[j];
            #pragma unroll
            for (int off = 32; off; off >>= 1) v += __shfl_xor(v, off);
            if ((tid & 63) == 0) red[tid >> 6][j] = v;
        }
        __syncthreads();
        if (tid < 7) {
            float s = red[0][tid] + red[1][tid] + red[2][tid] + red[3][tid];
            atomicAdd(&ws[OFF_LS + bc * 7 + tid], s);
        }
    }
}

// ================= final TV contraction: sum A[b,c,r,k]*t[b,r,k] =============
__global__ __launch_bounds__(256) void k_tv(const float* __restrict__ ws,
                                            float* __restrict__ acc_out) {
    const int bc = blockIdx.y;
    const int b = bc / 21;
    const int tid = threadIdx.x;
    __shared__ float4 fo4[256];
    const float4* src = (const float4*)(ws + OFF_FO + bc * NPIX);
    fo4[tid] = src[tid];
    __syncthreads();
    const int r = blockIdx.x * 256 + tid;
    const float v = ((const float*)fo4)[r];
    float ak[32];
    #pragma unroll
    for (int k = 0; k < 32; ++k) ak[k] = 0.f;
    #pragma unroll 4
    for (int h = 0; h < 32; ++h) {
        #pragma unroll
        for (int k4 = 0; k4 < 8; ++k4) {
            float4 f = fo4[h * 8 + k4];
            ak[k4 * 4 + 0] += fabsf(v - f.x);
            ak[k4 * 4 + 1] += fabsf(v - f.y);
            ak[k4 * 4 + 2] += fabsf(v - f.z);
            ak[k4 * 4 + 3] += fabsf(v - f.w);
        }
    }
    const float rm = ws[OFF_RMAX + b * 1024 + r];
    const float inv = 1.f / (rm + 1e-5f);
    const float* t = ws + OFF_GSUM + (b * 1024 + r) * 32;
    float dot = 0.f;
    #pragma unroll
    for (int k = 0; k < 32; ++k) dot += ak[k] * t[k];
    float part = dot * inv;
    #pragma unroll
    for (int off = 32; off; off >>= 1) part += __shfl_xor(part, off);
    __shared__ float red[4];
    if ((tid & 63) == 0) red[tid >> 6] = part;
    __syncthreads();
    if (tid == 0) atomicAdd(acc_out, red[0] + red[1] + red[2] + red[3]);
}

// ================= combine to 3 outputs ======================================
__global__ void k_combine(const float* __restrict__ ws, float* __restrict__ out) {
    const int tid = threadIdx.x;   // 128
    float v = 0.f;
    if (tid < NBC) {
        const float* p = ws + OFF_LS + tid * 7;
        float den = p[6];
        v = (p[3] + p[4] + p[5]) - (p[0]*p[0] + p[1]*p[1] + p[2]*p[2]) / den;
    }
    #pragma unroll
    for (int off = 32; off; off >>= 1) v += __shfl_xor(v, off);
    __shared__ float red[2];
    if ((tid & 63) == 0) red[tid >> 6] = v;
    __syncthreads();
    if (tid == 0) {
        float lsv = (red[0] + red[1]) * 0.25f;     // / B
        float tvv = ws[OFF_ACC] * 0.25f;           // / B
        out[0] = lsv * BETA_F;
        out[1] = tvv * LAMBDA_F * BETA_F;
        out[2] = (lsv + tvv * LAMBDA_F) * BETA_F;
    }
}

extern "C" void kernel_launch(void* const* d_in, const int* in_sizes, int n_in,
                              void* d_out, int out_size, void* d_ws, size_t ws_size,
                              hipStream_t stream) {
    const float* output   = (const float*)d_in[0];   // (4,21,512,512)
    const float* target   = (const float*)d_in[1];   // (4,3,512,512)
    const float* f_sem    = (const float*)d_in[2];   // (4,256,32,32)
    const float* f_output = (const float*)d_in[3];   // (4,21,64,64)
    // d_in[4] = use_NonLocal_TV, fixed to 1 by setup_inputs
    float* ws  = (float*)d_ws;
    float* out = (float*)d_out;

    hipLaunchKernelGGL(k_prep,    dim3(167),            dim3(256), 0, stream, f_output, f_sem, ws);
    hipLaunchKernelGGL(k_main,    dim3(N_GRAM_BLK+2688),dim3(256), 0, stream, output, target, f_sem, ws);
    hipLaunchKernelGGL(k_tv,      dim3(4, 84),          dim3(256), 0, stream, ws, ws + OFF_ACC);
    hipLaunchKernelGGL(k_combine, dim3(1),              dim3(128), 0, stream, ws, out);
}